// Round 11
// baseline (78.809 us; speedup 1.0000x reference)
//
#include <hip/hip_runtime.h>
#include <hip/hip_bf16.h>
#include <math.h>

#define NUM_EXPERTS 64
#define HIDDEN      4096
#define T_TOKENS    16384   // B*S
#define KSPLIT      8
#define TOKB        512     // tokens per gemm block (8 waves x 64)

using short8 = __attribute__((ext_vector_type(8))) short;   // 8 bf16
using f32x4  = __attribute__((ext_vector_type(4))) float;

// (f0,f1) -> packed bf16 hi (f0 in low 16) + packed bf16 lo residuals.
__device__ __forceinline__ unsigned pack_pair(float f0, float f1, unsigned& lopk) {
    __hip_bfloat162 h2 = __float22bfloat162_rn(make_float2(f0, f1));
    unsigned hb; __builtin_memcpy(&hb, &h2, 4);
    float h0 = __builtin_bit_cast(float, hb << 16);
    float h1 = __builtin_bit_cast(float, hb & 0xffff0000u);
    __hip_bfloat162 l2 = __float22bfloat162_rn(make_float2(f0 - h0, f1 - h1));
    unsigned lb; __builtin_memcpy(&lb, &l2, 4);
    lopk = lb;
    return hb;
}
__device__ __forceinline__ void split8(const float4 a, const float4 b, uint4& hi, uint4& lo) {
    hi.x = pack_pair(a.x, a.y, lo.x);
    hi.y = pack_pair(a.z, a.w, lo.y);
    hi.z = pack_pair(b.x, b.y, lo.z);
    hi.w = pack_pair(b.z, b.w, lo.w);
}

#define MFMA(a, b, c) __builtin_amdgcn_mfma_f32_16x16x32_bf16((a), (b), (c), 0, 0, 0)

// ---- pre-kernel: split W [64][4096] f32 into fragment-ordered bf16 hi/lo planes.
// Fragment j = ((t*4 + nt)*64 + lane): lane holds W[e = nt*16 + (lane&15)]
// [k = t*32 + (lane>>4)*8 .. +8].  hi at ws[j*16], lo at ws + 512KB + j*16.
__global__ __launch_bounds__(256) void w_split_kernel(
    const float* __restrict__ W, unsigned char* __restrict__ ws)
{
    const int j  = blockIdx.x * 256 + threadIdx.x;   // 0..32767
    const int l  = j & 63;
    const int nt = (j >> 6) & 3;
    const int t  = j >> 8;
    const int e  = nt * 16 + (l & 15);
    const int k0 = t * 32 + ((l >> 4) & 3) * 8;
    const float* p = W + (size_t)e * HIDDEN + k0;
    float4 w0 = *reinterpret_cast<const float4*>(p);
    float4 w1 = *reinterpret_cast<const float4*>(p + 4);
    uint4 hi, lo;
    split8(w0, w1, hi, lo);
    *reinterpret_cast<uint4*>(ws + (size_t)j * 16)            = hi;
    *reinterpret_cast<uint4*>(ws + 524288 + (size_t)j * 16)   = lo;
}

// ---- gemm kernel: block = 512 tokens (8 waves x 64), K-slice 512 (blockIdx.y).
// W K-slice staged ONCE into LDS (128 KB, hi+lo); main loop: A from global
// registers (vmcnt only), W from LDS (lgkmcnt only) -> zero main-loop barriers,
// A stream owns the entire vmem path.

#define LOAD_A4(dst, t_) do {                                                  \
    const float* pA_ = aBase + (size_t)(t_) * 32;                              \
    _Pragma("unroll")                                                          \
    for (int mt_ = 0; mt_ < 4; ++mt_) {                                        \
        dst[mt_][0] = *reinterpret_cast<const float4*>(pA_ + (size_t)mt_ * 16 * HIDDEN);     \
        dst[mt_][1] = *reinterpret_cast<const float4*>(pA_ + (size_t)mt_ * 16 * HIDDEN + 4); \
    } } while (0)

// Read one chunk's W fragments from LDS (hi 0..3, lo 4..7).
#define LDSW(dst, t_) do {                                                     \
    const unsigned char* pW_ = wlds + (size_t)(t_) * 4096 + laneOff;           \
    _Pragma("unroll")                                                          \
    for (int nt_ = 0; nt_ < 4; ++nt_) {                                        \
        dst[nt_]     = *reinterpret_cast<const uint4*>(pW_ + nt_ * 1024);      \
        dst[nt_ + 4] = *reinterpret_cast<const uint4*>(pW_ + 65536 + nt_ * 1024); \
    } } while (0)

#define CHUNK4(ab_, wb_) do {                                                  \
    _Pragma("unroll")                                                          \
    for (int mt_ = 0; mt_ < 4; ++mt_) {                                        \
        uint4 hi_, lo_;                                                        \
        split8(ab_[mt_][0], ab_[mt_][1], hi_, lo_);                            \
        short8 ah_ = __builtin_bit_cast(short8, hi_);                          \
        short8 al_ = __builtin_bit_cast(short8, lo_);                          \
        _Pragma("unroll")                                                      \
        for (int nt_ = 0; nt_ < 4; ++nt_) {                                    \
            short8 wh_ = __builtin_bit_cast(short8, wb_[nt_]);                 \
            short8 wl_ = __builtin_bit_cast(short8, wb_[nt_ + 4]);             \
            acc[mt_][nt_] = MFMA(ah_, wh_, acc[mt_][nt_]);                     \
            acc[mt_][nt_] = MFMA(ah_, wl_, acc[mt_][nt_]);                     \
            acc[mt_][nt_] = MFMA(al_, wh_, acc[mt_][nt_]);                     \
        } } } while (0)

__global__ __launch_bounds__(512, 2) void gemm_partial(
    const float* __restrict__ A,
    const unsigned char* __restrict__ wsHi,   // frag-ordered W hi; lo at +512KB
    float* __restrict__ part)                 // [T][KSPLIT][64] f32
{
    __shared__ unsigned char wlds[131072];    // hi 64KB | lo 64KB for this K-slice

    const int tid  = threadIdx.x;
    const int lane = tid & 63;
    const int w    = tid >> 6;                // wave id = M-subtile (0..7)
    const int ky   = blockIdx.y;              // K-slice (0..7)
    const int tok0 = blockIdx.x * TOKB + w * 64;

    // ---- stage W K-slice into LDS (128 KB), coalesced, one barrier ----
    {
        const unsigned char* srcH = wsHi + (size_t)ky * 65536;
        const unsigned char* srcL = wsHi + 524288 + (size_t)ky * 65536;
#pragma unroll
        for (int i = 0; i < 8; ++i) {
            const int off = (i * 512 + tid) * 16;
            *reinterpret_cast<uint4*>(&wlds[off]) =
                *reinterpret_cast<const uint4*>(&srcH[off]);
            *reinterpret_cast<uint4*>(&wlds[65536 + off]) =
                *reinterpret_cast<const uint4*>(&srcL[off]);
        }
    }
    __syncthreads();

    const float* aBase = A + (size_t)(tok0 + (lane & 15)) * HIDDEN
                           + ky * 512 + ((lane >> 4) & 3) * 8;
    const int laneOff = lane * 16;

    f32x4 acc[4][4];
#pragma unroll
    for (int mt = 0; mt < 4; ++mt)
#pragma unroll
        for (int nt = 0; nt < 4; ++nt) acc[mt][nt] = (f32x4){0.f, 0.f, 0.f, 0.f};

    float4 aX[4][2], aY[4][2];   // A ping-pong (1 chunk each)
    uint4  wP[8], wQ[8];         // W ping-pong from LDS

    LOAD_A4(aX, 0);
    LDSW(wP, 0);

    // 16 chunks, hand-unrolled ping-pong (static indices only).
    LOAD_A4(aY, 1);   LDSW(wQ, 1);   CHUNK4(aX, wP);   // t=0
    LOAD_A4(aX, 2);   LDSW(wP, 2);   CHUNK4(aY, wQ);   // t=1
    LOAD_A4(aY, 3);   LDSW(wQ, 3);   CHUNK4(aX, wP);   // t=2
    LOAD_A4(aX, 4);   LDSW(wP, 4);   CHUNK4(aY, wQ);   // t=3
    LOAD_A4(aY, 5);   LDSW(wQ, 5);   CHUNK4(aX, wP);   // t=4
    LOAD_A4(aX, 6);   LDSW(wP, 6);   CHUNK4(aY, wQ);   // t=5
    LOAD_A4(aY, 7);   LDSW(wQ, 7);   CHUNK4(aX, wP);   // t=6
    LOAD_A4(aX, 8);   LDSW(wP, 8);   CHUNK4(aY, wQ);   // t=7
    LOAD_A4(aY, 9);   LDSW(wQ, 9);   CHUNK4(aX, wP);   // t=8
    LOAD_A4(aX, 10);  LDSW(wP, 10);  CHUNK4(aY, wQ);   // t=9
    LOAD_A4(aY, 11);  LDSW(wQ, 11);  CHUNK4(aX, wP);   // t=10
    LOAD_A4(aX, 12);  LDSW(wP, 12);  CHUNK4(aY, wQ);   // t=11
    LOAD_A4(aY, 13);  LDSW(wQ, 13);  CHUNK4(aX, wP);   // t=12
    LOAD_A4(aX, 14);  LDSW(wP, 14);  CHUNK4(aY, wQ);   // t=13
    LOAD_A4(aY, 15);  LDSW(wQ, 15);  CHUNK4(aX, wP);   // t=14
                                     CHUNK4(aY, wQ);   // t=15

    // ---- store fp32 partials: part[tok][ky][e] ----
#pragma unroll
    for (int mt = 0; mt < 4; ++mt) {
#pragma unroll
        for (int nt = 0; nt < 4; ++nt) {
            const int e = nt * 16 + (lane & 15);
#pragma unroll
            for (int r = 0; r < 4; ++r) {
                const int tok = tok0 + mt * 16 + (lane >> 4) * 4 + r;
                part[((size_t)tok * KSPLIT + ky) * 64 + e] = acc[mt][nt][r];
            }
        }
    }
}

// ---- combine kernel: sum KSPLIT partials per token, top-2 ----
__global__ __launch_bounds__(64) void combine_topk(
    const float* __restrict__ part,   // [T][KSPLIT][64]
    float* __restrict__ out)
{
    const int tok = blockIdx.x * 64 + threadIdx.x;
    const float4* p = reinterpret_cast<const float4*>(part + (size_t)tok * KSPLIT * 64);

    float s[64];
#pragma unroll
    for (int i = 0; i < 16; ++i) {
        float4 v = p[i];
        s[4*i+0] = v.x; s[4*i+1] = v.y; s[4*i+2] = v.z; s[4*i+3] = v.w;
    }
#pragma unroll
    for (int sl = 1; sl < KSPLIT; ++sl) {
#pragma unroll
        for (int i = 0; i < 16; ++i) {
            float4 v = p[sl * 16 + i];
            s[4*i+0] += v.x; s[4*i+1] += v.y; s[4*i+2] += v.z; s[4*i+3] += v.w;
        }
    }

    float b1 = -INFINITY, b2 = -INFINITY;
    int i1 = 0, i2 = 0;
#pragma unroll
    for (int e = 0; e < NUM_EXPERTS; ++e) {
        float v = s[e];
        if (v > b1)      { b2 = b1; i2 = i1; b1 = v; i1 = e; }
        else if (v > b2) { b2 = v;  i2 = e; }
    }
    out[(size_t)tok * 2 + 0] = b1;
    out[(size_t)tok * 2 + 1] = b2;
    out[(size_t)2 * T_TOKENS + (size_t)tok * 2 + 0] = (float)i1;
    out[(size_t)2 * T_TOKENS + (size_t)tok * 2 + 1] = (float)i2;
}

extern "C" void kernel_launch(void* const* d_in, const int* in_sizes, int n_in,
                              void* d_out, int out_size, void* d_ws, size_t ws_size,
                              hipStream_t stream) {
    const float* A = (const float*)d_in[0];   // hidden_states fp32 [16384,4096]
    const float* W = (const float*)d_in[1];   // W fp32 [64,4096]
    float* out = (float*)d_out;
    unsigned char* ws = (unsigned char*)d_ws;
    // ws layout: [0,1MB) W hi/lo planes; [1MB, 1MB+32MB) fp32 partials
    float* part = reinterpret_cast<float*>(ws + (1 << 20));

    w_split_kernel<<<dim3(128), dim3(256), 0, stream>>>(W, ws);
    gemm_partial<<<dim3(T_TOKENS / TOKB, KSPLIT), dim3(512), 0, stream>>>(A, ws, part);
    combine_topk<<<dim3(T_TOKENS / 64), dim3(64), 0, stream>>>(part, out);
}

// Round 12
// 75.297 us; speedup vs baseline: 1.0466x; 1.0466x over previous
//
#include <hip/hip_runtime.h>
#include <hip/hip_bf16.h>
#include <math.h>

#define NUM_EXPERTS 64
#define HIDDEN      4096
#define T_TOKENS    16384   // B*S

using short8 = __attribute__((ext_vector_type(8))) short;   // 8 bf16
using f32x4  = __attribute__((ext_vector_type(4))) float;

// (f0,f1) -> packed bf16 hi (f0 in low 16) + packed bf16 lo residuals.
__device__ __forceinline__ unsigned pack_pair(float f0, float f1, unsigned& lopk) {
    __hip_bfloat162 h2 = __float22bfloat162_rn(make_float2(f0, f1));
    unsigned hb; __builtin_memcpy(&hb, &h2, 4);
    float h0 = __builtin_bit_cast(float, hb << 16);
    float h1 = __builtin_bit_cast(float, hb & 0xffff0000u);
    __hip_bfloat162 l2 = __float22bfloat162_rn(make_float2(f0 - h0, f1 - h1));
    unsigned lb; __builtin_memcpy(&lb, &l2, 4);
    lopk = lb;
    return hb;
}
__device__ __forceinline__ void split8(const float4 a, const float4 b, uint4& hi, uint4& lo) {
    hi.x = pack_pair(a.x, a.y, lo.x);
    hi.y = pack_pair(a.z, a.w, lo.y);
    hi.z = pack_pair(b.x, b.y, lo.z);
    hi.w = pack_pair(b.z, b.w, lo.w);
}

#define MFMA(a, b, c) __builtin_amdgcn_mfma_f32_16x16x32_bf16((a), (b), (c), 0, 0, 0)

// async global->LDS, 16 B per lane: LDS dest = uniform base + lane*16,
// global src = per-lane address. (m97 pattern; holds zero VGPRs.)
#define GLOAD16(g_, l_)                                                        \
    __builtin_amdgcn_global_load_lds(                                          \
        (__attribute__((address_space(1))) unsigned*)(void*)(g_),              \
        (__attribute__((address_space(3))) unsigned*)(void*)(l_), 16, 0, 0)

// ---- pre-kernel: split W [64][4096] f32 into fragment-ordered bf16 hi/lo planes.
// Fragment j = ((t*4 + nt)*64 + lane): lane holds W[e = nt*16 + (lane&15)]
// [k = t*32 + (lane>>4)*8 .. +8].  hi at ws[j*16], lo at ws + 512KB + j*16.
__global__ __launch_bounds__(256) void w_split_kernel(
    const float* __restrict__ W, unsigned char* __restrict__ ws)
{
    const int j  = blockIdx.x * 256 + threadIdx.x;   // 0..32767
    const int l  = j & 63;
    const int nt = (j >> 6) & 3;
    const int t  = j >> 8;
    const int e  = nt * 16 + (l & 15);
    const int k0 = t * 32 + ((l >> 4) & 3) * 8;
    const float* p = W + (size_t)e * HIDDEN + k0;
    float4 w0 = *reinterpret_cast<const float4*>(p);
    float4 w1 = *reinterpret_cast<const float4*>(p + 4);
    uint4 hi, lo;
    split8(w0, w1, hi, lo);
    *reinterpret_cast<uint4*>(ws + (size_t)j * 16)            = hi;
    *reinterpret_cast<uint4*>(ws + 524288 + (size_t)j * 16)   = lo;
}

// ---- main kernel: block = 64 tokens, 8 waves = K-split x8 (512 k each).
// A staged via global_load_lds into per-wave-private double buffers (no VGPR
// cost, allocator cannot sink the loads); W register ping-pong from L2;
// one barrier per chunk (m97 pattern: stage t+1 -> compute t -> barrier).

#define LOAD_W(dst, t_) do {                                                   \
    const unsigned char* pW_ = wsHi + (size_t)(tBase + (t_)) * 4096 + laneOff; \
    _Pragma("unroll")                                                          \
    for (int nt_ = 0; nt_ < 4; ++nt_) {                                        \
        dst[nt_]     = *reinterpret_cast<const uint4*>(pW_ + nt_ * 1024);      \
        dst[nt_ + 4] = *reinterpret_cast<const uint4*>(pW_ + 524288 + nt_ * 1024); \
    } } while (0)

// Stage one K=32 chunk of A (4 M-tiles) into buffer b_ (8 x global_load_lds).
#define STAGE_A(b_, t_) do {                                                   \
    unsigned char* ld_ = smem + (size_t)w * 16384 + (b_) * 8192;               \
    const float* g0_ = aBase + (size_t)(t_) * 32;                              \
    _Pragma("unroll")                                                          \
    for (int mt_ = 0; mt_ < 4; ++mt_) {                                        \
        const float* g_ = g0_ + (size_t)mt_ * 16 * HIDDEN;                     \
        GLOAD16(g_,     ld_ + mt_ * 2048);                                     \
        GLOAD16(g_ + 4, ld_ + mt_ * 2048 + 1024);                              \
    } } while (0)

// Compute one chunk: A fragments from LDS buffer b_, W from register buffer.
#define CHUNK_LDS(b_, wb_) do {                                                \
    const unsigned char* ls_ = smem + (size_t)w * 16384 + (b_) * 8192 + laneOff; \
    _Pragma("unroll")                                                          \
    for (int mt_ = 0; mt_ < 4; ++mt_) {                                        \
        float4 q0_ = *reinterpret_cast<const float4*>(ls_ + mt_ * 2048);       \
        float4 q1_ = *reinterpret_cast<const float4*>(ls_ + mt_ * 2048 + 1024);\
        uint4 hi_, lo_;                                                        \
        split8(q0_, q1_, hi_, lo_);                                            \
        short8 ah_ = __builtin_bit_cast(short8, hi_);                          \
        short8 al_ = __builtin_bit_cast(short8, lo_);                          \
        _Pragma("unroll")                                                      \
        for (int nt_ = 0; nt_ < 4; ++nt_) {                                    \
            short8 wh_ = __builtin_bit_cast(short8, wb_[nt_]);                 \
            short8 wl_ = __builtin_bit_cast(short8, wb_[nt_ + 4]);             \
            acc[mt_][nt_] = MFMA(ah_, wh_, acc[mt_][nt_]);                     \
            acc[mt_][nt_] = MFMA(ah_, wl_, acc[mt_][nt_]);                     \
            acc[mt_][nt_] = MFMA(al_, wh_, acc[mt_][nt_]);                     \
        } } } while (0)

__global__ __launch_bounds__(512, 2) void router_mfma_topk(
    const float* __restrict__ A,
    const unsigned char* __restrict__ wsHi,   // frag-ordered W hi; lo at +512KB
    float* __restrict__ out)
{
    // [0,128K): per-wave A staging (wave w: [w*16K, w*16K+16K), 2 x 8 KB bufs).
    // After the main loop, [0,64K) is reused as the combine scratch.
    __shared__ unsigned char smem[131072];

    const int tid  = threadIdx.x;
    const int lane = tid & 63;
    const int w    = tid >> 6;                // wave id = K-eighth (0..7)
    const int tok0 = blockIdx.x * 64;
    const int tBase = w * 16;                 // chunk base (chunks of K=32)

    const float* aBase = A + (size_t)(tok0 + (lane & 15)) * HIDDEN
                           + w * 512 + ((lane >> 4) & 3) * 8;
    const int laneOff = lane * 16;

    f32x4 acc[4][4];
#pragma unroll
    for (int mt = 0; mt < 4; ++mt)
#pragma unroll
        for (int nt = 0; nt < 4; ++nt) acc[mt][nt] = (f32x4){0.f, 0.f, 0.f, 0.f};

    uint4 wX[8], wY[8];          // W ping-pong (hi 0..3, lo 4..7)

    LOAD_W(wX, 0);
    STAGE_A(0, 0);
    __syncthreads();             // chunk 0 staged

    for (int tt = 0; tt < 8; ++tt) {          // 2 chunks per iteration
        const int t = tt * 2;
        LOAD_W(wY, t + 1);
        STAGE_A(1, t + 1);
        CHUNK_LDS(0, wX);                     // chunk t
        __syncthreads();                      // drains A(t+1) + W(t+1)
        if (tt < 7) { LOAD_W(wX, t + 2); STAGE_A(0, t + 2); }
        CHUNK_LDS(1, wY);                     // chunk t+1
        __syncthreads();
    }

    // ---- combine 8 K-eighths (reuse smem[0,64K)): waves 0-3 write, waves 4-7
    // RMW-add, then wave w<4 sums q=0..3 for its M-tile and does the top-2.
    f32x4 (*part)[4][4][64] = reinterpret_cast<f32x4 (*)[4][4][64]>(smem);

    if (w < 4) {
#pragma unroll
        for (int mt = 0; mt < 4; ++mt)
#pragma unroll
            for (int nt = 0; nt < 4; ++nt) part[w][mt][nt][lane] = acc[mt][nt];
    }
    __syncthreads();
    if (w >= 4) {
#pragma unroll
        for (int mt = 0; mt < 4; ++mt)
#pragma unroll
            for (int nt = 0; nt < 4; ++nt)
                part[w - 4][mt][nt][lane] = part[w - 4][mt][nt][lane] + acc[mt][nt];
    }
    __syncthreads();

    if (w < 4) {
        f32x4 s[4];
#pragma unroll
        for (int nt = 0; nt < 4; ++nt) {
            s[nt] = part[0][w][nt][lane];
#pragma unroll
            for (int q = 1; q < 4; ++q) s[nt] = s[nt] + part[q][w][nt][lane];
        }

        const int eBase = lane & 15;
#pragma unroll
        for (int r = 0; r < 4; ++r) {
            float b1 = s[0][r]; int i1 = eBase;
            float b2 = -INFINITY; int i2 = 0;
#pragma unroll
            for (int nt = 1; nt < 4; ++nt) {
                float v = s[nt][r];
                int   e = nt * 16 + eBase;
                if (v > b1)      { b2 = b1; i2 = i1; b1 = v; i1 = e; }
                else if (v > b2) { b2 = v;  i2 = e; }
            }
#pragma unroll
            for (int m = 1; m <= 8; m <<= 1) {
                float o1 = __shfl_xor(b1, m); int oi1 = __shfl_xor(i1, m);
                float o2 = __shfl_xor(b2, m); int oi2 = __shfl_xor(i2, m);
                float n1, c, n2; int ni1, ci, ni2;
                if (o1 > b1 || (o1 == b1 && oi1 < i1)) { n1 = o1; ni1 = oi1; c = b1; ci = i1; }
                else                                   { n1 = b1; ni1 = i1;  c = o1; ci = oi1; }
                if (b2 > o2 || (b2 == o2 && i2 < oi2)) { n2 = b2; ni2 = i2; }
                else                                   { n2 = o2; ni2 = oi2; }
                if (c > n2 || (c == n2 && ci < ni2))   { n2 = c;  ni2 = ci; }
                b1 = n1; i1 = ni1; b2 = n2; i2 = ni2;
            }
            if ((lane & 15) == 0) {
                const int tok = tok0 + w * 16 + (lane >> 4) * 4 + r;
                out[(size_t)tok * 2 + 0] = b1;
                out[(size_t)tok * 2 + 1] = b2;
                out[(size_t)2 * T_TOKENS + (size_t)tok * 2 + 0] = (float)i1;
                out[(size_t)2 * T_TOKENS + (size_t)tok * 2 + 1] = (float)i2;
            }
        }
    }
}

extern "C" void kernel_launch(void* const* d_in, const int* in_sizes, int n_in,
                              void* d_out, int out_size, void* d_ws, size_t ws_size,
                              hipStream_t stream) {
    const float* A = (const float*)d_in[0];   // hidden_states fp32 [16384,4096]
    const float* W = (const float*)d_in[1];   // W fp32 [64,4096]
    float* out = (float*)d_out;
    unsigned char* ws = (unsigned char*)d_ws; // 1 MB used (hi 512K + lo 512K)

    w_split_kernel<<<dim3(128), dim3(256), 0, stream>>>(W, ws);
    router_mfma_topk<<<dim3(T_TOKENS / 64), dim3(512), 0, stream>>>(A, ws, out);
}

// Round 13
// 64.192 us; speedup vs baseline: 1.2277x; 1.1730x over previous
//
#include <hip/hip_runtime.h>
#include <hip/hip_bf16.h>
#include <math.h>

#define NUM_EXPERTS 64
#define HIDDEN      4096
#define T_TOKENS    16384   // B*S

using short8 = __attribute__((ext_vector_type(8))) short;   // 8 bf16
using f32x4  = __attribute__((ext_vector_type(4))) float;

// (f0,f1) -> packed bf16 hi (f0 in low 16) + packed bf16 lo residuals.
__device__ __forceinline__ unsigned pack_pair(float f0, float f1, unsigned& lopk) {
    __hip_bfloat162 h2 = __float22bfloat162_rn(make_float2(f0, f1));
    unsigned hb; __builtin_memcpy(&hb, &h2, 4);
    float h0 = __builtin_bit_cast(float, hb << 16);
    float h1 = __builtin_bit_cast(float, hb & 0xffff0000u);
    __hip_bfloat162 l2 = __float22bfloat162_rn(make_float2(f0 - h0, f1 - h1));
    unsigned lb; __builtin_memcpy(&lb, &l2, 4);
    lopk = lb;
    return hb;
}
__device__ __forceinline__ void split8(const float4 a, const float4 b, uint4& hi, uint4& lo) {
    hi.x = pack_pair(a.x, a.y, lo.x);
    hi.y = pack_pair(a.z, a.w, lo.y);
    hi.z = pack_pair(b.x, b.y, lo.z);
    hi.w = pack_pair(b.z, b.w, lo.w);
}

#define MFMA(a, b, c) __builtin_amdgcn_mfma_f32_16x16x32_bf16((a), (b), (c), 0, 0, 0)

// async global->LDS, 16 B per lane (m97 pattern; holds zero VGPRs).
#define GLOAD16(g_, l_)                                                        \
    __builtin_amdgcn_global_load_lds(                                          \
        (__attribute__((address_space(1))) unsigned*)(void*)(g_),              \
        (__attribute__((address_space(3))) unsigned*)(void*)(l_), 16, 0, 0)

// ---- pre-kernel: split W [64][4096] f32 into fragment-ordered bf16 hi/lo planes.
__global__ __launch_bounds__(256) void w_split_kernel(
    const float* __restrict__ W, unsigned char* __restrict__ ws)
{
    const int j  = blockIdx.x * 256 + threadIdx.x;   // 0..32767
    const int l  = j & 63;
    const int nt = (j >> 6) & 3;
    const int t  = j >> 8;
    const int e  = nt * 16 + (l & 15);
    const int k0 = t * 32 + ((l >> 4) & 3) * 8;
    const float* p = W + (size_t)e * HIDDEN + k0;
    float4 w0 = *reinterpret_cast<const float4*>(p);
    float4 w1 = *reinterpret_cast<const float4*>(p + 4);
    uint4 hi, lo;
    split8(w0, w1, hi, lo);
    *reinterpret_cast<uint4*>(ws + (size_t)j * 16)            = hi;
    *reinterpret_cast<uint4*>(ws + 524288 + (size_t)j * 16)   = lo;
}

// ---- main kernel: block = 64 tokens, 8 waves = K-split x8 (512 k each).
// A staged via global_load_lds into WAVE-PRIVATE double buffers -> no
// __syncthreads in the main loop; sync is one counted `s_waitcnt vmcnt(8)`
// per chunk (leaves next A stage in flight). W register ping-pong from L2.

#define LOAD_W(dst, t_) do {                                                   \
    const unsigned char* pW_ = wsHi + (size_t)(tBase + (t_)) * 4096 + laneOff; \
    _Pragma("unroll")                                                          \
    for (int nt_ = 0; nt_ < 4; ++nt_) {                                        \
        dst[nt_]     = *reinterpret_cast<const uint4*>(pW_ + nt_ * 1024);      \
        dst[nt_ + 4] = *reinterpret_cast<const uint4*>(pW_ + 524288 + nt_ * 1024); \
    } } while (0)

// Stage one K=32 chunk of A (4 M-tiles) into wave-private buffer b_ (8 gload_lds).
#define STAGE_A(b_, t_) do {                                                   \
    unsigned char* ld_ = smem + (size_t)w * 16384 + (b_) * 8192;               \
    const float* g0_ = aBase + (size_t)(t_) * 32;                              \
    _Pragma("unroll")                                                          \
    for (int mt_ = 0; mt_ < 4; ++mt_) {                                        \
        const float* g_ = g0_ + (size_t)mt_ * 16 * HIDDEN;                     \
        GLOAD16(g_,     ld_ + mt_ * 2048);                                     \
        GLOAD16(g_ + 4, ld_ + mt_ * 2048 + 1024);                              \
    } } while (0)

// One chunk: wait A(t) (leave A-next in flight), ds_read, free buffer,
// issue W(t+1) + stage A(t+2) into the freed buffer, then split+MFMA.
#define ITER(t_, bufA_, wCur_, wNxt_) do {                                     \
    asm volatile("s_waitcnt vmcnt(8)" ::: "memory");                           \
    __builtin_amdgcn_sched_barrier(0);                                         \
    const unsigned char* ls_ = smem + (size_t)w * 16384 + (bufA_) * 8192 + laneOff; \
    float4 q_[4][2];                                                           \
    _Pragma("unroll")                                                          \
    for (int mt_ = 0; mt_ < 4; ++mt_) {                                        \
        q_[mt_][0] = *reinterpret_cast<const float4*>(ls_ + mt_ * 2048);       \
        q_[mt_][1] = *reinterpret_cast<const float4*>(ls_ + mt_ * 2048 + 1024);\
    }                                                                          \
    asm volatile("s_waitcnt lgkmcnt(0)" ::: "memory");                         \
    __builtin_amdgcn_sched_barrier(0);                                         \
    if ((t_) + 1 < 16) LOAD_W(wNxt_, (t_) + 1);                                \
    if ((t_) + 2 < 16) STAGE_A(bufA_, (t_) + 2);                               \
    _Pragma("unroll")                                                          \
    for (int mt_ = 0; mt_ < 4; ++mt_) {                                        \
        uint4 hi_, lo_;                                                        \
        split8(q_[mt_][0], q_[mt_][1], hi_, lo_);                              \
        short8 ah_ = __builtin_bit_cast(short8, hi_);                          \
        short8 al_ = __builtin_bit_cast(short8, lo_);                          \
        _Pragma("unroll")                                                      \
        for (int nt_ = 0; nt_ < 4; ++nt_) {                                    \
            short8 wh_ = __builtin_bit_cast(short8, wCur_[nt_]);               \
            short8 wl_ = __builtin_bit_cast(short8, wCur_[nt_ + 4]);           \
            acc[mt_][nt_] = MFMA(ah_, wh_, acc[mt_][nt_]);                     \
            acc[mt_][nt_] = MFMA(ah_, wl_, acc[mt_][nt_]);                     \
            acc[mt_][nt_] = MFMA(al_, wh_, acc[mt_][nt_]);                     \
        } }                                                                    \
} while (0)

__global__ __launch_bounds__(512, 2) void router_mfma_topk(
    const float* __restrict__ A,
    const unsigned char* __restrict__ wsHi,   // frag-ordered W hi; lo at +512KB
    float* __restrict__ out)
{
    // [0,128K): per-wave A staging (wave w: [w*16K, +16K), 2 x 8 KB buffers).
    // Reused as the 64 KB combine scratch after the main loop.
    __shared__ unsigned char smem[131072];

    const int tid  = threadIdx.x;
    const int lane = tid & 63;
    const int w    = tid >> 6;                // wave id = K-eighth (0..7)
    const int tok0 = blockIdx.x * 64;
    const int tBase = w * 16;                 // chunk base (chunks of K=32)

    const float* aBase = A + (size_t)(tok0 + (lane & 15)) * HIDDEN
                           + w * 512 + ((lane >> 4) & 3) * 8;
    const int laneOff = lane * 16;

    f32x4 acc[4][4];
#pragma unroll
    for (int mt = 0; mt < 4; ++mt)
#pragma unroll
        for (int nt = 0; nt < 4; ++nt) acc[mt][nt] = (f32x4){0.f, 0.f, 0.f, 0.f};

    uint4 wX[8], wY[8];          // W ping-pong (hi 0..3, lo 4..7)

    // Prologue: W(0) first (oldest), then A(0), A(1) -> vmcnt(8) at iter 0
    // drains W0+A0 and leaves A1 in flight.
    LOAD_W(wX, 0);
    STAGE_A(0, 0);
    STAGE_A(1, 1);

    ITER( 0, 0, wX, wY);  ITER( 1, 1, wY, wX);
    ITER( 2, 0, wX, wY);  ITER( 3, 1, wY, wX);
    ITER( 4, 0, wX, wY);  ITER( 5, 1, wY, wX);
    ITER( 6, 0, wX, wY);  ITER( 7, 1, wY, wX);
    ITER( 8, 0, wX, wY);  ITER( 9, 1, wY, wX);
    ITER(10, 0, wX, wY);  ITER(11, 1, wY, wX);
    ITER(12, 0, wX, wY);  ITER(13, 1, wY, wX);
    ITER(14, 0, wX, wY);  ITER(15, 1, wY, wX);

    // ---- combine 8 K-eighths (reuse smem[0,64K)): waves 0-3 write, waves 4-7
    // RMW-add, then wave w<4 sums q=0..3 for its M-tile and does the top-2.
    f32x4 (*part)[4][4][64] = reinterpret_cast<f32x4 (*)[4][4][64]>(smem);

    __syncthreads();             // first barrier: all staging drained (vmcnt 0)
    if (w < 4) {
#pragma unroll
        for (int mt = 0; mt < 4; ++mt)
#pragma unroll
            for (int nt = 0; nt < 4; ++nt) part[w][mt][nt][lane] = acc[mt][nt];
    }
    __syncthreads();
    if (w >= 4) {
#pragma unroll
        for (int mt = 0; mt < 4; ++mt)
#pragma unroll
            for (int nt = 0; nt < 4; ++nt)
                part[w - 4][mt][nt][lane] = part[w - 4][mt][nt][lane] + acc[mt][nt];
    }
    __syncthreads();

    if (w < 4) {
        f32x4 s[4];
#pragma unroll
        for (int nt = 0; nt < 4; ++nt) {
            s[nt] = part[0][w][nt][lane];
#pragma unroll
            for (int q = 1; q < 4; ++q) s[nt] = s[nt] + part[q][w][nt][lane];
        }

        const int eBase = lane & 15;
#pragma unroll
        for (int r = 0; r < 4; ++r) {
            float b1 = s[0][r]; int i1 = eBase;
            float b2 = -INFINITY; int i2 = 0;
#pragma unroll
            for (int nt = 1; nt < 4; ++nt) {
                float v = s[nt][r];
                int   e = nt * 16 + eBase;
                if (v > b1)      { b2 = b1; i2 = i1; b1 = v; i1 = e; }
                else if (v > b2) { b2 = v;  i2 = e; }
            }
#pragma unroll
            for (int m = 1; m <= 8; m <<= 1) {
                float o1 = __shfl_xor(b1, m); int oi1 = __shfl_xor(i1, m);
                float o2 = __shfl_xor(b2, m); int oi2 = __shfl_xor(i2, m);
                float n1, c, n2; int ni1, ci, ni2;
                if (o1 > b1 || (o1 == b1 && oi1 < i1)) { n1 = o1; ni1 = oi1; c = b1; ci = i1; }
                else                                   { n1 = b1; ni1 = i1;  c = o1; ci = oi1; }
                if (b2 > o2 || (b2 == o2 && i2 < oi2)) { n2 = b2; ni2 = i2; }
                else                                   { n2 = o2; ni2 = oi2; }
                if (c > n2 || (c == n2 && ci < ni2))   { n2 = c;  ni2 = ci; }
                b1 = n1; i1 = ni1; b2 = n2; i2 = ni2;
            }
            if ((lane & 15) == 0) {
                const int tok = tok0 + w * 16 + (lane >> 4) * 4 + r;
                out[(size_t)tok * 2 + 0] = b1;
                out[(size_t)tok * 2 + 1] = b2;
                out[(size_t)2 * T_TOKENS + (size_t)tok * 2 + 0] = (float)i1;
                out[(size_t)2 * T_TOKENS + (size_t)tok * 2 + 1] = (float)i2;
            }
        }
    }
}

extern "C" void kernel_launch(void* const* d_in, const int* in_sizes, int n_in,
                              void* d_out, int out_size, void* d_ws, size_t ws_size,
                              hipStream_t stream) {
    const float* A = (const float*)d_in[0];   // hidden_states fp32 [16384,4096]
    const float* W = (const float*)d_in[1];   // W fp32 [64,4096]
    float* out = (float*)d_out;
    unsigned char* ws = (unsigned char*)d_ws; // 1 MB used (hi 512K + lo 512K)

    w_split_kernel<<<dim3(128), dim3(256), 0, stream>>>(W, ws);
    router_mfma_topk<<<dim3(T_TOKENS / 64), dim3(512), 0, stream>>>(A, ws, out);
}

// Round 14
// 61.161 us; speedup vs baseline: 1.2886x; 1.0496x over previous
//
#include <hip/hip_runtime.h>
#include <hip/hip_bf16.h>
#include <math.h>

#define NUM_EXPERTS 64
#define HIDDEN      4096
#define T_TOKENS    16384   // B*S

using short8 = __attribute__((ext_vector_type(8))) short;   // 8 bf16
using f32x4  = __attribute__((ext_vector_type(4))) float;

// (f0,f1) -> packed bf16 hi (f0 in low 16) + packed bf16 lo residuals.
__device__ __forceinline__ unsigned pack_pair(float f0, float f1, unsigned& lopk) {
    __hip_bfloat162 h2 = __float22bfloat162_rn(make_float2(f0, f1));
    unsigned hb; __builtin_memcpy(&hb, &h2, 4);
    float h0 = __builtin_bit_cast(float, hb << 16);
    float h1 = __builtin_bit_cast(float, hb & 0xffff0000u);
    __hip_bfloat162 l2 = __float22bfloat162_rn(make_float2(f0 - h0, f1 - h1));
    unsigned lb; __builtin_memcpy(&lb, &l2, 4);
    lopk = lb;
    return hb;
}
__device__ __forceinline__ void split8(const float4 a, const float4 b, uint4& hi, uint4& lo) {
    hi.x = pack_pair(a.x, a.y, lo.x);
    hi.y = pack_pair(a.z, a.w, lo.y);
    hi.z = pack_pair(b.x, b.y, lo.z);
    hi.w = pack_pair(b.z, b.w, lo.w);
}

#define MFMA(a, b, c) __builtin_amdgcn_mfma_f32_16x16x32_bf16((a), (b), (c), 0, 0, 0)

// async global->LDS, 16 B per lane (zero VGPR cost).
#define GLOAD16(g_, l_)                                                        \
    __builtin_amdgcn_global_load_lds(                                          \
        (__attribute__((address_space(1))) unsigned*)(void*)(g_),              \
        (__attribute__((address_space(3))) unsigned*)(void*)(l_), 16, 0, 0)

#define WAITVM(n_)  asm volatile("s_waitcnt vmcnt(" #n_ ")" ::: "memory")
#define WAITLG()    asm volatile("s_waitcnt lgkmcnt(0)" ::: "memory")
#define SB()        __builtin_amdgcn_sched_barrier(0)

// ---- pre-kernel: split W [64][4096] f32 into fragment-ordered bf16 hi/lo planes.
// Fragment j = ((t*4 + nt)*64 + lane), t = global K-chunk (k/32).
__global__ __launch_bounds__(256) void w_split_kernel(
    const float* __restrict__ W, unsigned char* __restrict__ ws)
{
    const int j  = blockIdx.x * 256 + threadIdx.x;   // 0..32767
    const int l  = j & 63;
    const int nt = (j >> 6) & 3;
    const int t  = j >> 8;
    const int e  = nt * 16 + (l & 15);
    const int k0 = t * 32 + ((l >> 4) & 3) * 8;
    const float* p = W + (size_t)e * HIDDEN + k0;
    float4 w0 = *reinterpret_cast<const float4*>(p);
    float4 w1 = *reinterpret_cast<const float4*>(p + 4);
    uint4 hi, lo;
    split8(w0, w1, hi, lo);
    *reinterpret_cast<uint4*>(ws + (size_t)j * 16)            = hi;
    *reinterpret_cast<uint4*>(ws + 524288 + (size_t)j * 16)   = lo;
}

// ---- main kernel: block = 128 tokens x K-half (blockIdx.y); 4 waves, each
// owning a K-eighth-of-total (512 k = 16 chunks) across 8 M-tiles.
// W traffic: T/BM MB = 128 MB (halved vs BM=64). R13's counted-vmcnt
// wave-private staging pipeline, scaled to 16-KB chunks / vmcnt(16).

#define LOAD_W(dst, t_) do {                                                   \
    const unsigned char* pW_ = wsHi + (size_t)(tBase + (t_)) * 4096 + laneOff; \
    _Pragma("unroll")                                                          \
    for (int nt_ = 0; nt_ < 4; ++nt_) {                                        \
        dst[nt_]     = *reinterpret_cast<const uint4*>(pW_ + nt_ * 1024);      \
        dst[nt_ + 4] = *reinterpret_cast<const uint4*>(pW_ + 524288 + nt_ * 1024); \
    } } while (0)

// Stage one K=32 chunk of A (8 M-tiles) into wave-private buffer b_ (16 gload_lds).
#define STAGE_A8(b_, t_) do {                                                  \
    unsigned char* ld_ = smem + (size_t)w * 32768 + (b_) * 16384;              \
    const float* g0_ = aBase + (size_t)(t_) * 32;                              \
    _Pragma("unroll")                                                          \
    for (int mt_ = 0; mt_ < 8; ++mt_) {                                        \
        const float* g_ = g0_ + (size_t)mt_ * 16 * HIDDEN;                     \
        GLOAD16(g_,     ld_ + mt_ * 2048);                                     \
        GLOAD16(g_ + 4, ld_ + mt_ * 2048 + 1024);                              \
    } } while (0)

// ds_read + split + 12 MFMA for M-tiles mt0_..mt0_+3 from LDS base ls_.
#define SUB_READ(q_, ls_, mt0_) do {                                           \
    _Pragma("unroll")                                                          \
    for (int i_ = 0; i_ < 4; ++i_) {                                           \
        q_[i_][0] = *reinterpret_cast<const float4*>((ls_) + (mt0_ + i_) * 2048);        \
        q_[i_][1] = *reinterpret_cast<const float4*>((ls_) + (mt0_ + i_) * 2048 + 1024); \
    } } while (0)

#define SUB_MFMA(q_, mt0_, wb_) do {                                           \
    _Pragma("unroll")                                                          \
    for (int i_ = 0; i_ < 4; ++i_) {                                           \
        uint4 hi_, lo_;                                                        \
        split8(q_[i_][0], q_[i_][1], hi_, lo_);                                \
        short8 ah_ = __builtin_bit_cast(short8, hi_);                          \
        short8 al_ = __builtin_bit_cast(short8, lo_);                          \
        _Pragma("unroll")                                                      \
        for (int nt_ = 0; nt_ < 4; ++nt_) {                                    \
            short8 wh_ = __builtin_bit_cast(short8, wb_[nt_]);                 \
            short8 wl_ = __builtin_bit_cast(short8, wb_[nt_ + 4]);             \
            acc[mt0_ + i_][nt_] = MFMA(ah_, wh_, acc[mt0_ + i_][nt_]);         \
            acc[mt0_ + i_][nt_] = MFMA(ah_, wl_, acc[mt0_ + i_][nt_]);         \
            acc[mt0_ + i_][nt_] = MFMA(al_, wh_, acc[mt0_ + i_][nt_]);         \
        } } } while (0)

// One chunk. Steady state: entering, outstanding = [A(t),W(t),A(t+1)] = 40;
// vmcnt(16) drains A(t)+W(t), leaves A(t+1) in flight.
#define ITER_BODY(t_, buf_, wCur_, wNxt_) do {                                 \
    SB();                                                                      \
    const unsigned char* ls_ = smem + (size_t)w * 32768 + (buf_) * 16384 + laneOff; \
    float4 qA_[4][2];                                                          \
    SUB_READ(qA_, ls_, 0);                                                     \
    WAITLG(); SB();                                                            \
    if ((t_) + 1 < 16) LOAD_W(wNxt_, (t_) + 1);                                \
    SUB_MFMA(qA_, 0, wCur_);                                                   \
    float4 qB_[4][2];                                                          \
    SUB_READ(qB_, ls_, 4);                                                     \
    WAITLG(); SB();                                                            \
    if ((t_) + 2 < 16) STAGE_A8(buf_, (t_) + 2);                               \
    SUB_MFMA(qB_, 4, wCur_);                                                   \
} while (0)

#define ITER(t_, buf_, wCur_, wNxt_)      do { WAITVM(16); ITER_BODY(t_, buf_, wCur_, wNxt_); } while (0)
#define ITER_LAST(t_, buf_, wCur_, wNxt_) do { WAITVM(0);  ITER_BODY(t_, buf_, wCur_, wNxt_); } while (0)

__global__ __launch_bounds__(256, 1) void router_gemm_partial(
    const float* __restrict__ A,
    const unsigned char* __restrict__ wsHi,   // frag-ordered W hi; lo at +512KB
    float* __restrict__ partG)                // [2][T][64] f32
{
    // [0,128K): per-wave A staging (wave w: [w*32K, +32K), 2 x 16 KB buffers).
    // Reused as the 128 KB in-block combine scratch after the main loop.
    __shared__ unsigned char smem[131072];

    const int tid  = threadIdx.x;
    const int lane = tid & 63;
    const int w    = tid >> 6;                // wave id = K-quarter of half (0..3)
    const int ky   = blockIdx.y;              // K-half (0..1)
    const int tok0 = blockIdx.x * 128;
    const int tBase = ky * 64 + w * 16;       // global chunk base (chunks of 32k)

    const float* aBase = A + (size_t)(tok0 + (lane & 15)) * HIDDEN
                           + ky * 2048 + w * 512 + ((lane >> 4) & 3) * 8;
    const int laneOff = lane * 16;

    f32x4 acc[8][4];
#pragma unroll
    for (int mt = 0; mt < 8; ++mt)
#pragma unroll
        for (int nt = 0; nt < 4; ++nt) acc[mt][nt] = (f32x4){0.f, 0.f, 0.f, 0.f};

    uint4 wX[8], wY[8];          // W ping-pong (hi 0..3, lo 4..7)

    // Prologue: W(0) first (oldest), then A(0), A(1).
    LOAD_W(wX, 0);
    STAGE_A8(0, 0);
    STAGE_A8(1, 1);

    ITER( 0, 0, wX, wY);  ITER( 1, 1, wY, wX);
    ITER( 2, 0, wX, wY);  ITER( 3, 1, wY, wX);
    ITER( 4, 0, wX, wY);  ITER( 5, 1, wY, wX);
    ITER( 6, 0, wX, wY);  ITER( 7, 1, wY, wX);
    ITER( 8, 0, wX, wY);  ITER( 9, 1, wY, wX);
    ITER(10, 0, wX, wY);  ITER(11, 1, wY, wX);
    ITER(12, 0, wX, wY);  ITER(13, 1, wY, wX);
    ITER(14, 0, wX, wY);  ITER_LAST(15, 1, wY, wX);

    // ---- in-block combine over 4 K-quarters (reuse smem as part[4][8][4][64])
    f32x4 (*part)[8][4][64] = reinterpret_cast<f32x4 (*)[8][4][64]>(smem);

    __syncthreads();
#pragma unroll
    for (int mt = 0; mt < 8; ++mt)
#pragma unroll
        for (int nt = 0; nt < 4; ++nt) part[w][mt][nt][lane] = acc[mt][nt];
    __syncthreads();

    // wave w reduces M-tiles 2w, 2w+1 and writes fp32 partials to global.
#pragma unroll
    for (int j = 0; j < 2; ++j) {
        const int mt = 2 * w + j;
#pragma unroll
        for (int nt = 0; nt < 4; ++nt) {
            f32x4 s = part[0][mt][nt][lane];
#pragma unroll
            for (int q = 1; q < 4; ++q) s = s + part[q][mt][nt][lane];
            const int e = nt * 16 + (lane & 15);
#pragma unroll
            for (int r = 0; r < 4; ++r) {
                const int tok = tok0 + mt * 16 + (lane >> 4) * 4 + r;
                partG[((size_t)ky * T_TOKENS + tok) * 64 + e] = s[r];
            }
        }
    }
}

// ---- combine kernel: sum the 2 K-halves per token, top-2 ----
__global__ __launch_bounds__(64) void combine_topk(
    const float* __restrict__ partG,   // [2][T][64]
    float* __restrict__ out)
{
    const int tok = blockIdx.x * 64 + threadIdx.x;
    const float4* p0 = reinterpret_cast<const float4*>(partG + (size_t)tok * 64);
    const float4* p1 = reinterpret_cast<const float4*>(partG + ((size_t)T_TOKENS + tok) * 64);

    float s[64];
#pragma unroll
    for (int i = 0; i < 16; ++i) {
        float4 a = p0[i], b = p1[i];
        s[4*i+0] = a.x + b.x; s[4*i+1] = a.y + b.y;
        s[4*i+2] = a.z + b.z; s[4*i+3] = a.w + b.w;
    }

    float b1 = -INFINITY, b2 = -INFINITY;
    int i1 = 0, i2 = 0;
#pragma unroll
    for (int e = 0; e < NUM_EXPERTS; ++e) {
        float v = s[e];
        if (v > b1)      { b2 = b1; i2 = i1; b1 = v; i1 = e; }
        else if (v > b2) { b2 = v;  i2 = e; }
    }
    out[(size_t)tok * 2 + 0] = b1;
    out[(size_t)tok * 2 + 1] = b2;
    out[(size_t)2 * T_TOKENS + (size_t)tok * 2 + 0] = (float)i1;
    out[(size_t)2 * T_TOKENS + (size_t)tok * 2 + 1] = (float)i2;
}

extern "C" void kernel_launch(void* const* d_in, const int* in_sizes, int n_in,
                              void* d_out, int out_size, void* d_ws, size_t ws_size,
                              hipStream_t stream) {
    const float* A = (const float*)d_in[0];   // hidden_states fp32 [16384,4096]
    const float* W = (const float*)d_in[1];   // W fp32 [64,4096]
    float* out = (float*)d_out;
    unsigned char* ws = (unsigned char*)d_ws;
    // ws layout: [0,1MB) W hi/lo planes; [1MB, 1MB+8MB) fp32 partials [2][T][64]
    float* partG = reinterpret_cast<float*>(ws + (1 << 20));

    w_split_kernel<<<dim3(128), dim3(256), 0, stream>>>(W, ws);
    router_gemm_partial<<<dim3(T_TOKENS / 128, 2), dim3(256), 0, stream>>>(A, ws, partG);
    combine_topk<<<dim3(T_TOKENS / 64), dim3(64), 0, stream>>>(partG, out);
}